// Round 9
// baseline (1579.544 us; speedup 1.0000x reference)
//
#include <hip/hip_runtime.h>
#include <hip/hip_bf16.h>

// GRU forward v9 — v8 (all weights resident, 1 wave/SIMD) + gates in LDS.
//   Round-8 lesson: weights fit (256 AGPR + 128 VGPR pins, correct output)
//   but the 96 gate VGPRs (cur+next prefetch) pushed arch-VGPR demand to
//   ~300 -> VGPR_Count=256 cap -> ~40-reg scratch spill in the loop ->
//   2.74us/step. v9 evicts gates to a 48KB LDS double-buffer via
//   global_load_lds (v4-proven mechanism) with COUNTED vmcnt (v4's bug was
//   draining to 0): loads for t+1 issued at top of step t (6/wave), stores
//   (4) at end -> wait vmcnt(10) before reading step-t gates; tail vmcnt(4).
//   Each wave loads/reads only its own sU slice -> no barrier for gates.
//   Working set ~230 arch VGPRs: slack, no spill.

typedef _Float16 f16;
typedef _Float16 half4 __attribute__((ext_vector_type(4)));
typedef _Float16 half8 __attribute__((ext_vector_type(8)));
typedef float floatx4 __attribute__((ext_vector_type(4)));

#define MFMA16(a, b, c) __builtin_amdgcn_mfma_f32_16x16x32_f16((a), (b), (c), 0, 0, 0)

// ---- workspace layout (bytes) ----
#define WTAB_OFF   0u          // W frags  [g3][nt16][ktx2][lane64][16B]      = 98304
#define RZG_OFF    98304u      // H frags  [tid256][g3][nti4][kt8][16B]       = 393216
#define PRE_OFF    491520u     // pre-gates [bid 8176][gc6][tid256][16B]      = 200933376
#define WS_NEED    (491520ull + 200933376ull)

typedef const __attribute__((address_space(1))) unsigned int* gp1;
typedef __attribute__((address_space(3))) unsigned int* lp3;

// =====================================================================
// prep: weight-fragment tables (30720 half8)
//   frag(g, nt, kt, lane) = H_g[k][nt*16 + (lane&15)], k = kt*32+(lane>>4)*8+i
// =====================================================================
__global__ void gru_wprep(const float* __restrict__ Wr, const float* __restrict__ Wz,
                          const float* __restrict__ Wg, const float* __restrict__ Hr,
                          const float* __restrict__ Hz, const float* __restrict__ Hg,
                          f16* __restrict__ ws) {
    int idx = blockIdx.x * 256 + threadIdx.x;   // 0..30719
    if (idx >= 30720) return;
    const float* src;
    int col, k0;
    f16* dst;
    if (idx < 6144) {                            // Wtab: ((g*16+nt)*2+ktx)*64+lane
        int lane = idx & 63, ktx = (idx >> 6) & 1, nt = (idx >> 7) & 15, g = idx >> 11;
        src = (g == 0) ? Wr : (g == 1) ? Wz : Wg;
        col = nt * 16 + (lane & 15);
        k0  = ktx * 32 + (lane >> 4) * 8;
        dst = ws + WTAB_OFF / 2 + (size_t)idx * 8;
    } else {                                     // RZG: tid*96 + g*32 + nti*8 + kt
        int local = idx - 6144;                  // 0..24575
        int kt = local & 7, nti = (local >> 3) & 3;
        int rest = local >> 5;                   // tid*3 + g
        int g = rest % 3, tid = rest / 3;
        int l = tid & 63;
        src = (g == 0) ? Hr : (g == 1) ? Hz : Hg;
        col = ((tid >> 6) * 4 + nti) * 16 + (l & 15);
        k0  = kt * 32 + (l >> 4) * 8;
        dst = ws + RZG_OFF / 2 + (size_t)local * 8;
    }
    half8 v;
#pragma unroll
    for (int i = 0; i < 8; ++i) v[i] = (f16)src[(size_t)(k0 + i) * 256 + col];
    *(half8*)dst = v;
}

// =====================================================================
// prep: pre-gates (transposed MFMA: A=W-frag, B=x-frag), 256 threads.
//   Thread owns (m = l&15, cols n = (w*4+nti)*16 + rq*4 + j).
//   Store: pre[bid][gc = g*2+c][tid] half8; elem e -> nti = c*2+(e>>2), j = e&3.
// =====================================================================
__global__ void __launch_bounds__(256)
gru_gates(const float* __restrict__ x, const float* __restrict__ br,
          const float* __restrict__ bz, const float* __restrict__ bg,
          f16* __restrict__ ws) {
    const int bid = blockIdx.x;                  // t*16 + blk, t in [0,511)
    const int t = bid >> 4, blk = bid & 15;
    const int tid = threadIdx.x, w = tid >> 6, l = tid & 63;
    const int m = l & 15, rq = l >> 4;

    half8 xb[2];
    const float* xr = x + (size_t)(blk * 16 + m) * 32768 + (size_t)t * 64 + rq * 8;
#pragma unroll
    for (int ktx = 0; ktx < 2; ++ktx) {
        float4 a = *(const float4*)(xr + ktx * 32);
        float4 b = *(const float4*)(xr + ktx * 32 + 4);
        half8 v;
        v[0] = (f16)a.x; v[1] = (f16)a.y; v[2] = (f16)a.z; v[3] = (f16)a.w;
        v[4] = (f16)b.x; v[5] = (f16)b.y; v[6] = (f16)b.z; v[7] = (f16)b.w;
        xb[ktx] = v;
    }

    const half8* Wt = (const half8*)(ws + WTAB_OFF / 2);
    floatx4 acc[3][4];
#pragma unroll
    for (int g = 0; g < 3; ++g)
#pragma unroll
        for (int nti = 0; nti < 4; ++nti) {
            int n0 = (w * 4 + nti) * 16 + rq * 4;
            float4 bv = *(const float4*)((g == 0 ? br : g == 1 ? bz : bg) + n0);
            acc[g][nti] = (floatx4){bv.x, bv.y, bv.z, bv.w};
        }
#pragma unroll
    for (int g = 0; g < 3; ++g)
#pragma unroll
        for (int nti = 0; nti < 4; ++nti) {
            int nt = w * 4 + nti;
#pragma unroll
            for (int ktx = 0; ktx < 2; ++ktx)
                acc[g][nti] = MFMA16(Wt[(size_t)((g * 16 + nt) * 2 + ktx) * 64 + l], xb[ktx],
                                     acc[g][nti]);
        }

    half8* preb = (half8*)(ws + PRE_OFF / 2);
#pragma unroll
    for (int g = 0; g < 3; ++g)
#pragma unroll
        for (int c = 0; c < 2; ++c) {
            half8 v;
#pragma unroll
            for (int e = 0; e < 8; ++e)
                v[e] = (f16)acc[g][c * 2 + (e >> 2)][e & 3];
            preb[(size_t)(bid * 6 + g * 2 + c) * 256 + tid] = v;
        }
}

// =====================================================================
// scan v9: 16 WGs x 256 threads (4 waves, 1/SIMD), weights resident,
//          gates via global_load_lds dbuf + counted vmcnt
// =====================================================================

#define WLOAD9(kt) \
    half8 hr_##kt##_0 = rzg[0*32 + 0*8 + kt], hr_##kt##_1 = rzg[0*32 + 1*8 + kt], \
          hr_##kt##_2 = rzg[0*32 + 2*8 + kt], hr_##kt##_3 = rzg[0*32 + 3*8 + kt]; \
    half8 hz_##kt##_0 = rzg[1*32 + 0*8 + kt], hz_##kt##_1 = rzg[1*32 + 1*8 + kt], \
          hz_##kt##_2 = rzg[1*32 + 2*8 + kt], hz_##kt##_3 = rzg[1*32 + 3*8 + kt]; \
    half8 hg_##kt##_0 = rzg[2*32 + 0*8 + kt], hg_##kt##_1 = rzg[2*32 + 1*8 + kt], \
          hg_##kt##_2 = rzg[2*32 + 2*8 + kt], hg_##kt##_3 = rzg[2*32 + 3*8 + kt]; \
    asm volatile("" : "+a"(hr_##kt##_0), "+a"(hr_##kt##_1), "+a"(hr_##kt##_2), "+a"(hr_##kt##_3), \
                      "+a"(hz_##kt##_0), "+a"(hz_##kt##_1), "+a"(hz_##kt##_2), "+a"(hz_##kt##_3)); \
    asm volatile("" : "+v"(hg_##kt##_0), "+v"(hg_##kt##_1), "+v"(hg_##kt##_2), "+v"(hg_##kt##_3));

#define PA9(kt) { \
    half8 hv = *(const half8*)(sH + hbase + (((kt) * 64 + rq * 16) ^ hsw)); \
    aR0 = MFMA16(hr_##kt##_0, hv, aR0);  aZ0 = MFMA16(hz_##kt##_0, hv, aZ0); \
    aR1 = MFMA16(hr_##kt##_1, hv, aR1);  aZ1 = MFMA16(hz_##kt##_1, hv, aZ1); \
    aR2 = MFMA16(hr_##kt##_2, hv, aR2);  aZ2 = MFMA16(hz_##kt##_2, hv, aZ2); \
    aR3 = MFMA16(hr_##kt##_3, hv, aR3);  aZ3 = MFMA16(hz_##kt##_3, hv, aZ3); }

#define PB9(kt) { \
    half8 hv = *(const half8*)(sRH + hbase + (((kt) * 64 + rq * 16) ^ hsw)); \
    aG0 = MFMA16(hg_##kt##_0, hv, aG0); \
    aG1 = MFMA16(hg_##kt##_1, hv, aG1); \
    aG2 = MFMA16(hg_##kt##_2, hv, aG2); \
    aG3 = MFMA16(hg_##kt##_3, hv, aG3); }

// epilogue A for one nti: r,z; write r*h (8B) to sRH
#define EPIA9(nti, AR, AZ, U0, U1, ZH) { \
    half4 p; \
    _Pragma("unroll") \
    for (int j = 0; j < 4; ++j) { \
        const int e = ((nti) & 1) * 4 + j; \
        float r = __builtin_amdgcn_rcpf(1.f + __expf(-(AR[j] + (float)U0[e]))); \
        float z = __builtin_amdgcn_rcpf(1.f + __expf(-(AZ[j] + (float)U1[e]))); \
        ZH[j] = (f16)z; \
        p[j] = (f16)(r * h[nti][j]); \
    } \
    *(half4*)(sRH + wb##nti) = p; }

// epilogue B for one nti: g=tanh, blend, write h (8B) + out (float4)
#define EPIB9(nti, AG, U2, ZH) { \
    half4 p; float4 o; \
    _Pragma("unroll") \
    for (int j = 0; j < 4; ++j) { \
        const int e = ((nti) & 1) * 4 + j; \
        float ex = __expf(2.f * (AG[j] + (float)U2[e])); \
        float g = 1.f - 2.f * __builtin_amdgcn_rcpf(ex + 1.f); \
        float hn = h[nti][j] + (float)ZH[j] * (g - h[nti][j]); \
        h[nti][j] = hn; \
        p[j] = (f16)hn; \
        ((float*)&o)[j] = hn; \
    } \
    *(half4*)(sH + wb##nti) = p; \
    *(float4*)(op + n##nti) = o; }

__global__ __attribute__((amdgpu_waves_per_eu(1, 1))) void __launch_bounds__(256)
gru_scan9(const f16* __restrict__ ws, float* __restrict__ out) {
    __shared__ __align__(16) unsigned char sH[8192];    // h   f16 [16][256] swizzled
    __shared__ __align__(16) unsigned char sRH[8192];   // r*h f16 [16][256] swizzled
    __shared__ __align__(16) unsigned char sU[49152];   // gates dbuf [2][gc6][tid256][16B]

    const int tid = threadIdx.x, w = tid >> 6, l = tid & 63;
    const int m = l & 15, rq = l >> 4;
    const int blk = blockIdx.x, b0 = blk * 16;
    const int n0 = (w * 4 + 0) * 16 + rq * 4;
    const int n1 = (w * 4 + 1) * 16 + rq * 4;
    const int n2 = (w * 4 + 2) * 16 + rq * 4;
    const int n3 = (w * 4 + 3) * 16 + rq * 4;
    const unsigned char* wsb = (const unsigned char*)ws;

    // ---- weights: 96 named half8/thread; hr,hz -> 256 AGPR, hg -> 128 VGPR ----
    const half8* rzg = (const half8*)(ws + RZG_OFF / 2) + (size_t)tid * 96;
    WLOAD9(0) WLOAD9(1) WLOAD9(2) WLOAD9(3) WLOAD9(4) WLOAD9(5) WLOAD9(6) WLOAD9(7)

    // ---- zero sH; zero out[:,0,:] ----
    { uint4 z = {}; ((uint4*)sH)[tid] = z; ((uint4*)sH)[256 + tid] = z; }
#pragma unroll
    for (int i = 0; i < 16; ++i) {
        int q = i * 256 + tid;
        out[(size_t)(b0 + (q >> 8)) * 131072 + (q & 255)] = 0.f;
    }

    // ---- prologue: gates for t=0 into sU buf0 ----
    {
        const unsigned char* gsrc = wsb + PRE_OFF + (size_t)blk * 24576 + (size_t)tid * 16;
        unsigned char* gdst = sU + w * 1024;
#pragma unroll
        for (int gc = 0; gc < 6; ++gc)
            __builtin_amdgcn_global_load_lds((gp1)(const void*)(gsrc + gc * 4096),
                                             (lp3)(void*)(gdst + gc * 4096), 16, 0, 0);
    }

    float h[4][4] = {};                  // h at (m, n<nti>+j), fp32 master
    half4 zs0, zs1, zs2, zs3;            // z gates, f16

    asm volatile("s_waitcnt vmcnt(0) lgkmcnt(0)" ::: "memory");
    __builtin_amdgcn_s_barrier();
    __builtin_amdgcn_sched_barrier(0);

    const int hbase = m * 512;           // h row stride 512B
    const int hsw   = (m & 7) << 4;      // XOR swizzle for this row
    const int wb0 = hbase + ((n0 * 2) ^ hsw);
    const int wb1 = hbase + ((n1 * 2) ^ hsw);
    const int wb2 = hbase + ((n2 * 2) ^ hsw);
    const int wb3 = hbase + ((n3 * 2) ^ hsw);

    float* op = out + (size_t)(b0 + m) * 131072 + 256;   // out[b0+m][t=1][0]

    for (int t = 0; t < 511; ++t) {
        const int buf = (t & 1) * 24576;

        // ---- issue next step's gate loads into the other buffer (6 VM/wave) ----
        if (t < 510) {
            const unsigned char* gsrc = wsb + PRE_OFF
                                        + (size_t)((t + 1) * 16 + blk) * 24576
                                        + (size_t)tid * 16;
            unsigned char* gdst = sU + (24576 - buf) + w * 1024;
#pragma unroll
            for (int gc = 0; gc < 6; ++gc)
                __builtin_amdgcn_global_load_lds((gp1)(const void*)(gsrc + gc * 4096),
                                                 (lp3)(void*)(gdst + gc * 4096), 16, 0, 0);
        }

        // ---- phase A: R,Z pre-activations (A=hr/hz from AGPR, B=h from sH) ----
        floatx4 aR0 = {}, aR1 = {}, aR2 = {}, aR3 = {};
        floatx4 aZ0 = {}, aZ1 = {}, aZ2 = {}, aZ3 = {};
        PA9(0) PA9(1) PA9(2) PA9(3) PA9(4) PA9(5) PA9(6) PA9(7)

        // ---- counted vmcnt: drain L(t) only (leave 4 stores + 6 new loads) ----
        if (t < 510) { asm volatile("s_waitcnt vmcnt(10)" ::: "memory"); }
        else         { asm volatile("s_waitcnt vmcnt(4)"  ::: "memory"); }

        // ---- epilogue A: gates u0,u1 from sU (wave-local), r,z, write r*h ----
        {
            const unsigned char* gub = sU + buf + tid * 16;
            half8 u0a = *(const half8*)(gub);
            half8 u0b = *(const half8*)(gub + 4096);
            half8 u1a = *(const half8*)(gub + 8192);
            half8 u1b = *(const half8*)(gub + 12288);
            EPIA9(0, aR0, aZ0, u0a, u1a, zs0)
            EPIA9(1, aR1, aZ1, u0a, u1a, zs1)
            EPIA9(2, aR2, aZ2, u0b, u1b, zs2)
            EPIA9(3, aR3, aZ3, u0b, u1b, zs3)
        }

        asm volatile("s_waitcnt lgkmcnt(0)" ::: "memory");
        __builtin_amdgcn_s_barrier();
        __builtin_amdgcn_sched_barrier(0);

        // ---- phase B: G pre-activation (A=hg from VGPR, B=rh from sRH) ----
        floatx4 aG0 = {}, aG1 = {}, aG2 = {}, aG3 = {};
        PB9(0) PB9(1) PB9(2) PB9(3) PB9(4) PB9(5) PB9(6) PB9(7)

        // ---- epilogue B: u2 from sU, g=tanh, blend, write h + out ----
        {
            const unsigned char* gub = sU + buf + tid * 16;
            half8 u2a = *(const half8*)(gub + 16384);
            half8 u2b = *(const half8*)(gub + 20480);
            EPIB9(0, aG0, u2a, zs0)
            EPIB9(1, aG1, u2a, zs1)
            EPIB9(2, aG2, u2b, zs2)
            EPIB9(3, aG3, u2b, zs3)
        }
        op += 256;

        asm volatile("s_waitcnt lgkmcnt(0)" ::: "memory");
        __builtin_amdgcn_s_barrier();
        __builtin_amdgcn_sched_barrier(0);
    }
}

// =====================================================================
// v1 fallback (round-1 kernels, proven correct) — used if ws too small
// =====================================================================
__global__ void gru_prep(const float* __restrict__ Wr, const float* __restrict__ Wz,
                         const float* __restrict__ Wg, const float* __restrict__ Hr,
                         const float* __restrict__ Hz, const float* __restrict__ Hg,
                         f16* __restrict__ B) {
    int idx = blockIdx.x * 256 + threadIdx.x;
    int lane = idx & 63;
    int rest = idx >> 6;
    int kt = rest % 10;
    rest /= 10;
    int nt = rest & 15;
    int g  = rest >> 4;
    if (g >= 3) return;
    const float* H = (g == 0) ? Hr : (g == 1) ? Hz : Hg;
    const float* W = (g == 0) ? Wr : (g == 1) ? Wz : Wg;
    int col   = nt * 16 + (lane & 15);
    int kbase = kt * 32 + (lane >> 4) * 8;
    half8 v;
#pragma unroll
    for (int i = 0; i < 8; ++i) {
        int k = kbase + i;
        float val = (k < 256) ? H[k * 256 + col] : W[(k - 256) * 256 + col];
        v[i] = (f16)val;
    }
    *(half8*)(B + (size_t)idx * 8) = v;
}

__global__ void __launch_bounds__(512, 1)
gru_scan(const float* __restrict__ x,
         const float* __restrict__ br, const float* __restrict__ bz,
         const float* __restrict__ bg,
         const f16* __restrict__ Bfrag,
         float* __restrict__ out) {
    __shared__ __align__(16) unsigned char sH[8192];
    __shared__ __align__(16) unsigned char sRH[8192];
    __shared__ __align__(16) unsigned char sX[2][2048];

    const int tid  = threadIdx.x;
    const int wave = tid >> 6;
    const int lane = tid & 63;
    const int cl   = lane & 15;
    const int rq   = lane >> 4;
    const int b0   = blockIdx.x * 16;
    const int nt0  = wave * 2, nt1 = wave * 2 + 1;
    const int col0 = nt0 * 16 + cl, col1 = nt1 * 16 + cl;

    const int abase = cl * 512;
    const int asw   = (cl & 7) << 4;

    const float bR0 = br[col0], bR1 = br[col1];
    const float bZ0 = bz[col0], bZ1 = bz[col1];
    const float bG0 = bg[col0], bG1 = bg[col1];

    const half8* Bb  = (const half8*)Bfrag;
    const half8* pR0 = Bb + (size_t)((0 * 16 + nt0) * 10) * 64 + lane;
    const half8* pR1 = Bb + (size_t)((0 * 16 + nt1) * 10) * 64 + lane;
    const half8* pZ0 = Bb + (size_t)((1 * 16 + nt0) * 10) * 64 + lane;
    const half8* pZ1 = Bb + (size_t)((1 * 16 + nt1) * 10) * 64 + lane;
    const half8* pG0 = Bb + (size_t)((2 * 16 + nt0) * 10) * 64 + lane;
    const half8* pG1 = Bb + (size_t)((2 * 16 + nt1) * 10) * 64 + lane;

    float h0_[4] = {0.f, 0.f, 0.f, 0.f};
    float h1_[4] = {0.f, 0.f, 0.f, 0.f};
    float zs0[4], zs1[4];

    { half8 zz = {}; *(half8*)(sH + tid * 16) = zz; }
    for (int i = tid; i < 16 * 256; i += 512) {
        int r = i >> 8, c = i & 255;
        out[((size_t)(b0 + r) * 512) * 256 + c] = 0.f;
    }
    {
        size_t xo = (size_t)(b0 + wave) * 32768 + lane;
        float a0 = x[xo], a1 = x[xo + (size_t)8 * 32768];
        *(f16*)(sX[0] + wave * 128       + ((lane * 2) ^ ((wave & 7) << 4))) = (f16)a0;
        *(f16*)(sX[0] + (wave + 8) * 128 + ((lane * 2) ^ ((wave & 7) << 4))) = (f16)a1;
    }
    __syncthreads();

    for (int t = 0; t < 511; ++t) {
        const int xb = t & 1;
        float xp0 = 0.f, xp1 = 0.f;
        if (t < 510) {
            size_t xo = (size_t)(b0 + wave) * 32768 + (size_t)(t + 1) * 64 + lane;
            xp0 = x[xo];
            xp1 = x[xo + (size_t)8 * 32768];
        }

        floatx4 aR0 = {0,0,0,0}, aR1 = {0,0,0,0}, aZ0 = {0,0,0,0}, aZ1 = {0,0,0,0};
        half8 xa0, xa1;
#pragma unroll
        for (int kt = 0; kt < 8; ++kt) {
            half8 av = *(const half8*)(sH + abase + ((kt * 64 + rq * 16) ^ asw));
            aR0 = MFMA16(av, pR0[kt * 64], aR0);
            aR1 = MFMA16(av, pR1[kt * 64], aR1);
            aZ0 = MFMA16(av, pZ0[kt * 64], aZ0);
            aZ1 = MFMA16(av, pZ1[kt * 64], aZ1);
        }
        xa0 = *(const half8*)(sX[xb] + cl * 128 + ((rq * 16) ^ asw));
        xa1 = *(const half8*)(sX[xb] + cl * 128 + ((64 + rq * 16) ^ asw));
        aR0 = MFMA16(xa0, pR0[8 * 64], aR0);  aR1 = MFMA16(xa0, pR1[8 * 64], aR1);
        aZ0 = MFMA16(xa0, pZ0[8 * 64], aZ0);  aZ1 = MFMA16(xa0, pZ1[8 * 64], aZ1);
        aR0 = MFMA16(xa1, pR0[9 * 64], aR0);  aR1 = MFMA16(xa1, pR1[9 * 64], aR1);
        aZ0 = MFMA16(xa1, pZ0[9 * 64], aZ0);  aZ1 = MFMA16(xa1, pZ1[9 * 64], aZ1);

        if (t < 510) {
            const int nb = xb ^ 1;
            *(f16*)(sX[nb] + wave * 128       + ((lane * 2) ^ ((wave & 7) << 4))) = (f16)xp0;
            *(f16*)(sX[nb] + (wave + 8) * 128 + ((lane * 2) ^ ((wave & 7) << 4))) = (f16)xp1;
        }

#pragma unroll
        for (int j = 0; j < 4; ++j) {
            const int row = rq * 4 + j;
            float r0 = 1.f / (1.f + __expf(-(aR0[j] + bR0)));
            float r1 = 1.f / (1.f + __expf(-(aR1[j] + bR1)));
            zs0[j]   = 1.f / (1.f + __expf(-(aZ0[j] + bZ0)));
            zs1[j]   = 1.f / (1.f + __expf(-(aZ1[j] + bZ1)));
            const int sw = (row & 7) << 4;
            *(f16*)(sRH + row * 512 + ((col0 * 2) ^ sw)) = (f16)(r0 * h0_[j]);
            *(f16*)(sRH + row * 512 + ((col1 * 2) ^ sw)) = (f16)(r1 * h1_[j]);
        }
        __syncthreads();

        floatx4 aG0 = {0,0,0,0}, aG1 = {0,0,0,0};
#pragma unroll
        for (int kt = 0; kt < 8; ++kt) {
            half8 av = *(const half8*)(sRH + abase + ((kt * 64 + rq * 16) ^ asw));
            aG0 = MFMA16(av, pG0[kt * 64], aG0);
            aG1 = MFMA16(av, pG1[kt * 64], aG1);
        }
        aG0 = MFMA16(xa0, pG0[8 * 64], aG0);  aG1 = MFMA16(xa0, pG1[8 * 64], aG1);
        aG0 = MFMA16(xa1, pG0[9 * 64], aG0);  aG1 = MFMA16(xa1, pG1[9 * 64], aG1);

#pragma unroll
        for (int j = 0; j < 4; ++j) {
            const int row = rq * 4 + j;
            float e0 = __expf(2.f * (aG0[j] + bG0));
            float g0 = 1.f - 2.f / (e0 + 1.f);
            float e1 = __expf(2.f * (aG1[j] + bG1));
            float g1 = 1.f - 2.f / (e1 + 1.f);
            float hn0 = h0_[j] + zs0[j] * (g0 - h0_[j]);
            float hn1 = h1_[j] + zs1[j] * (g1 - h1_[j]);
            h0_[j] = hn0;
            h1_[j] = hn1;
            const int sw = (row & 7) << 4;
            *(f16*)(sH + row * 512 + ((col0 * 2) ^ sw)) = (f16)hn0;
            *(f16*)(sH + row * 512 + ((col1 * 2) ^ sw)) = (f16)hn1;
            size_t ob = ((size_t)(b0 + row) * 512 + (t + 1)) * 256;
            out[ob + col0] = hn0;
            out[ob + col1] = hn1;
        }
        __syncthreads();
    }
}

extern "C" void kernel_launch(void* const* d_in, const int* in_sizes, int n_in,
                              void* d_out, int out_size, void* d_ws, size_t ws_size,
                              hipStream_t stream) {
    const float* x  = (const float*)d_in[0];
    const float* Wr = (const float*)d_in[1];
    const float* br = (const float*)d_in[2];
    const float* Wz = (const float*)d_in[3];
    const float* bz = (const float*)d_in[4];
    const float* Wg = (const float*)d_in[5];
    const float* bg = (const float*)d_in[6];
    const float* Hr = (const float*)d_in[7];
    const float* Hz = (const float*)d_in[8];
    const float* Hg = (const float*)d_in[9];
    float* out = (float*)d_out;

    if (ws_size >= WS_NEED) {
        f16* ws = (f16*)d_ws;
        gru_wprep<<<120, 256, 0, stream>>>(Wr, Wz, Wg, Hr, Hz, Hg, ws);
        gru_gates<<<511 * 16, 256, 0, stream>>>(x, br, bz, bg, ws);
        gru_scan9<<<16, 256, 0, stream>>>(ws, out);
    } else {
        f16* Bfrag = (f16*)d_ws;
        gru_prep<<<120, 256, 0, stream>>>(Wr, Wz, Wg, Hr, Hz, Hg, Bfrag);
        gru_scan<<<16, 512, 0, stream>>>(x, br, bz, bg, Bfrag, out);
    }
}

// Round 10
// 1142.436 us; speedup vs baseline: 1.3826x; 1.3826x over previous
//
#include <hip/hip_runtime.h>
#include <hip/hip_bf16.h>

// GRU forward v10 — v3 base (proven 983us scan) + critical-path rebalance.
//   9-round summary: weights must be CU-resident (r1-2); at 2 waves/SIMD the
//   per-wave budget is 256 regs total so only rz fits in AGPR pins, Hg in LDS
//   (v3, 1.92us/step, 124 VGPR); 1 wave/SIMD is latency-exposed and slower
//   (v8/v9 ~2.9us/step) regardless of residency.
//   v10 insight: the GRU chain is h -> r-gemm -> rh -> g-gemm -> blend; the
//   Z-GEMM IS OFF THE CRITICAL PATH (z only needed at the blend). Move z-gemm
//   + z-sigmoid from phase A to phase B: phase A = r only (16 MFMA + 8
//   sigmoids/wave), phase B = z+g gemms overlapped. sH double-buffered
//   (phase B reads h(t-1) while epilogue writes h(t)). All else = v3 verbatim.

typedef _Float16 f16;
typedef _Float16 half8 __attribute__((ext_vector_type(8)));
typedef float floatx4 __attribute__((ext_vector_type(4)));

#define MFMA16(a, b, c) __builtin_amdgcn_mfma_f32_16x16x32_f16((a), (b), (c), 0, 0, 0)

// ---- workspace layout (bytes) ----
#define WTAB_OFF   0u          // W frags  [g3][nt16][ktx2][lane64][16B]       = 98304
#define RZTAB_OFF  98304u      // RZ frags [tid512][g2][nti2][kt8][16B]        = 262144
#define GTAB_OFF   360448u     // Hg frags [nt16][kt8][lane64][16B]            = 131072
#define PRE_OFF    491520u     // pre-gates [bid 8176][g3][tid512][16B]        = 200933376
#define WS_NEED    (491520ull + 200933376ull)

// =====================================================================
// prep: weight-fragment tables (30720 half8)  [round-3 verbatim]
// =====================================================================
__global__ void gru_wprep(const float* __restrict__ Wr, const float* __restrict__ Wz,
                          const float* __restrict__ Wg, const float* __restrict__ Hr,
                          const float* __restrict__ Hz, const float* __restrict__ Hg,
                          f16* __restrict__ ws) {
    int idx = blockIdx.x * 256 + threadIdx.x;   // 0..30719
    if (idx >= 30720) return;
    const float* src;
    int col, k0;
    f16* dst;
    if (idx < 6144) {                            // Wtab: ((g*16+nt)*2+ktx)*64+lane
        int lane = idx & 63, ktx = (idx >> 6) & 1, nt = (idx >> 7) & 15, g = idx >> 11;
        src = (g == 0) ? Wr : (g == 1) ? Wz : Wg;
        col = nt * 16 + (lane & 15);
        k0  = ktx * 32 + (lane >> 4) * 8;
        dst = ws + WTAB_OFF / 2 + (size_t)idx * 8;
    } else if (idx < 22528) {                    // RZtab: tid*32 + g*16 + nti*8 + kt
        int local = idx - 6144;
        int kt = local & 7, nti = (local >> 3) & 1, g = (local >> 4) & 1, tid = local >> 5;
        int w = tid >> 6, l = tid & 63;
        src = g ? Hz : Hr;
        col = (w * 2 + nti) * 16 + (l & 15);
        k0  = kt * 32 + (l >> 4) * 8;
        dst = ws + RZTAB_OFF / 2 + (size_t)local * 8;
    } else {                                     // Gtab: (nt*8+kt)*64+lane
        int local = idx - 22528;                 // 0..8191
        int lane = local & 63, q = local >> 6;
        int kt = q & 7, nt = q >> 3;
        src = Hg;
        col = nt * 16 + (lane & 15);
        k0  = kt * 32 + (lane >> 4) * 8;
        dst = ws + GTAB_OFF / 2 + (size_t)local * 8;
    }
    half8 v;
#pragma unroll
    for (int i = 0; i < 8; ++i) v[i] = (f16)src[(size_t)(k0 + i) * 256 + col];
    *(half8*)dst = v;
}

// =====================================================================
// prep: pre-gates  pre[bid][g][tid512] = (x_t @ W_g + b_g) D-frag, f16
//   [round-3 verbatim: non-transposed, A = x-frag]
// =====================================================================
__global__ void __launch_bounds__(512)
gru_gates(const float* __restrict__ x, const float* __restrict__ br,
          const float* __restrict__ bz, const float* __restrict__ bg,
          f16* __restrict__ ws) {
    const int bid = blockIdx.x;                  // t*16 + blk, t in [0,511)
    const int t = bid >> 4, blk = bid & 15;
    const int tid = threadIdx.x, w = tid >> 6, l = tid & 63;
    const int cl = l & 15, rq = l >> 4;

    half8 xa[2];
    const float* xr = x + (size_t)(blk * 16 + cl) * 32768 + (size_t)t * 64 + rq * 8;
#pragma unroll
    for (int ktx = 0; ktx < 2; ++ktx) {
        float4 a = *(const float4*)(xr + ktx * 32);
        float4 b = *(const float4*)(xr + ktx * 32 + 4);
        half8 v;
        v[0] = (f16)a.x; v[1] = (f16)a.y; v[2] = (f16)a.z; v[3] = (f16)a.w;
        v[4] = (f16)b.x; v[5] = (f16)b.y; v[6] = (f16)b.z; v[7] = (f16)b.w;
        xa[ktx] = v;
    }

    const half8* Wt = (const half8*)(ws + WTAB_OFF / 2);
    floatx4 acc[3][2];
#pragma unroll
    for (int g = 0; g < 3; ++g)
#pragma unroll
        for (int nti = 0; nti < 2; ++nti) {
            int col = (w * 2 + nti) * 16 + cl;
            float b = (g == 0 ? br : g == 1 ? bz : bg)[col];
            acc[g][nti] = (floatx4){b, b, b, b};
        }
#pragma unroll
    for (int g = 0; g < 3; ++g)
#pragma unroll
        for (int nti = 0; nti < 2; ++nti) {
            int nt = w * 2 + nti;
#pragma unroll
            for (int ktx = 0; ktx < 2; ++ktx)
                acc[g][nti] = MFMA16(xa[ktx], Wt[(size_t)((g * 16 + nt) * 2 + ktx) * 64 + l],
                                     acc[g][nti]);
        }

    half8* preb = (half8*)(ws + PRE_OFF / 2);
#pragma unroll
    for (int g = 0; g < 3; ++g) {
        half8 v;
#pragma unroll
        for (int nti = 0; nti < 2; ++nti)
#pragma unroll
            for (int j = 0; j < 4; ++j)
                v[nti * 4 + j] = (f16)acc[g][nti][j];
        preb[((size_t)bid * 3 + g) * 512 + tid] = v;
    }
}

// =====================================================================
// scan v10: 16 WGs x 512 threads (8 waves, 2/SIMD)
//   phase A: r-gemm only; phase B: z-gemm + g-gemm; sH double-buffered
// =====================================================================
__global__ void __launch_bounds__(512, 2)
gru_scan10(const f16* __restrict__ ws, float* __restrict__ out) {
    extern __shared__ unsigned char smem[];
    unsigned char* sHB = smem;               // 16384  : h f16 [2][16][256] swizzled dbuf
    unsigned char* sRH = smem + 16384;       // 8192   : r*h f16 [16][256] swizzled
    unsigned char* sG  = smem + 24576;       // 131072 : Hg frags [nt16][kt8][lane64][16B]

    const int tid = threadIdx.x, w = tid >> 6, l = tid & 63;
    const int cl = l & 15, rq = l >> 4;
    const int blk = blockIdx.x, b0 = blk * 16;

    // ---- register-resident Hr,Hz fragments (128 regs, pinned; v3-proven) ----
    half8 rz[2][2][8];
    {
        const half8* rzt = (const half8*)(ws + RZTAB_OFF / 2) + (size_t)tid * 32;
#pragma unroll
        for (int g = 0; g < 2; ++g)
#pragma unroll
            for (int nti = 0; nti < 2; ++nti)
#pragma unroll
                for (int kt = 0; kt < 8; ++kt)
                    rz[g][nti][kt] = rzt[g * 16 + nti * 8 + kt];
    }
#pragma unroll
    for (int g = 0; g < 2; ++g)
#pragma unroll
        for (int nti = 0; nti < 2; ++nti)
#pragma unroll
            for (int kt = 0; kt < 8; ++kt)
                asm volatile("" : "+v"(rz[g][nti][kt]));   // pin: block remat

    // ---- stage Hg into LDS (128KB) ----
    {
        const uint4* src = (const uint4*)(ws + GTAB_OFF / 2);
        uint4* dst = (uint4*)sG;
#pragma unroll
        for (int i = 0; i < 16; ++i) dst[tid + i * 512] = src[tid + i * 512];
    }
    // ---- zero sH buf0; zero out[:,0,:] ----
    { uint4 z = {}; ((uint4*)sHB)[tid] = z; }
    for (int i = tid; i < 4096; i += 512) {
        int row = i >> 8, col = i & 255;
        out[(size_t)(b0 + row) * 131072 + col] = 0.f;
    }

    float h[2][4] = {};

    const half8* preb = (const half8*)(ws + PRE_OFF / 2);
    half8 ucur[3], unxt[3] = {};
#pragma unroll
    for (int g = 0; g < 3; ++g)
        ucur[g] = preb[((size_t)blk * 3 + g) * 512 + tid];

    asm volatile("s_waitcnt lgkmcnt(0)" ::: "memory");
    __builtin_amdgcn_s_barrier();
    __builtin_amdgcn_sched_barrier(0);

    const int abase = cl * 512;
    const int asw   = (cl & 7) << 4;

    for (int t = 0; t < 511; ++t) {
        const unsigned char* sHc = sHB + (t & 1) * 8192;        // h(t-1)
        unsigned char*       sHn = sHB + ((t + 1) & 1) * 8192;  // h(t)

        // prefetch next step's gates into registers (counted vmcnt, no drain)
        if (t < 510) {
            const half8* p = preb + ((size_t)((t + 1) * 16 + blk) * 3) * 512 + tid;
#pragma unroll
            for (int g = 0; g < 3; ++g) unxt[g] = p[g * 512];
        }

        // ---- phase A: R pre-activation only (critical path) ----
        floatx4 aR[2] = {};
#pragma unroll
        for (int kt = 0; kt < 8; ++kt) {
            half8 av = *(const half8*)(sHc + abase + ((kt * 64 + rq * 16) ^ asw));
#pragma unroll
            for (int nti = 0; nti < 2; ++nti)
                aR[nti] = MFMA16(av, rz[0][nti][kt], aR[nti]);
        }

        // ---- epilogue A: r = sigmoid; write r*h (f16) to sRH ----
#pragma unroll
        for (int nti = 0; nti < 2; ++nti) {
            int col = (w * 2 + nti) * 16 + cl;
#pragma unroll
            for (int j = 0; j < 4; ++j) {
                int row = rq * 4 + j;
                int e = nti * 4 + j;
                float r = __builtin_amdgcn_rcpf(1.f + __expf(-(aR[nti][j] + (float)ucur[0][e])));
                *(f16*)(sRH + row * 512 + ((col * 2) ^ ((row & 7) << 4))) = (f16)(r * h[nti][j]);
            }
        }
        asm volatile("s_waitcnt lgkmcnt(0)" ::: "memory");
        __builtin_amdgcn_s_barrier();
        __builtin_amdgcn_sched_barrier(0);

        // ---- phase B: Z-gemm (off critical path, reads h(t-1)) + G-gemm ----
        floatx4 aZ[2] = {}, aG[2] = {};
#pragma unroll
        for (int kt = 0; kt < 8; ++kt) {
            half8 avh = *(const half8*)(sHc + abase + ((kt * 64 + rq * 16) ^ asw));
            half8 avr = *(const half8*)(sRH + abase + ((kt * 64 + rq * 16) ^ asw));
#pragma unroll
            for (int nti = 0; nti < 2; ++nti) {
                int nt = w * 2 + nti;
                half8 bf = *(const half8*)(sG + (size_t)((nt * 8 + kt) * 64 + l) * 16);
                aZ[nti] = MFMA16(avh, rz[1][nti][kt], aZ[nti]);
                aG[nti] = MFMA16(avr, bf, aG[nti]);
            }
        }

        // ---- epilogue B: z=sigmoid, g=tanh, blend, write h(t) + out ----
#pragma unroll
        for (int nti = 0; nti < 2; ++nti) {
            int col = (w * 2 + nti) * 16 + cl;
#pragma unroll
            for (int j = 0; j < 4; ++j) {
                int row = rq * 4 + j;
                int e = nti * 4 + j;
                float z = __builtin_amdgcn_rcpf(1.f + __expf(-(aZ[nti][j] + (float)ucur[1][e])));
                float ex = __expf(2.f * (aG[nti][j] + (float)ucur[2][e]));
                float g = 1.f - 2.f * __builtin_amdgcn_rcpf(ex + 1.f);  // tanh, inf-safe
                float hn = h[nti][j] + z * (g - h[nti][j]);
                h[nti][j] = hn;
                *(f16*)(sHn + row * 512 + ((col * 2) ^ ((row & 7) << 4))) = (f16)hn;
                out[(size_t)(b0 + row) * 131072 + (size_t)(t + 1) * 256 + col] = hn;
            }
        }
#pragma unroll
        for (int g = 0; g < 3; ++g) ucur[g] = unxt[g];
        asm volatile("s_waitcnt lgkmcnt(0)" ::: "memory");
        __builtin_amdgcn_s_barrier();
        __builtin_amdgcn_sched_barrier(0);
    }
}

// =====================================================================
// v1 fallback (round-1 kernels, proven correct) — used if ws too small
// =====================================================================
__global__ void gru_prep(const float* __restrict__ Wr, const float* __restrict__ Wz,
                         const float* __restrict__ Wg, const float* __restrict__ Hr,
                         const float* __restrict__ Hz, const float* __restrict__ Hg,
                         f16* __restrict__ B) {
    int idx = blockIdx.x * 256 + threadIdx.x;
    int lane = idx & 63;
    int rest = idx >> 6;
    int kt = rest % 10;
    rest /= 10;
    int nt = rest & 15;
    int g  = rest >> 4;
    if (g >= 3) return;
    const float* H = (g == 0) ? Hr : (g == 1) ? Hz : Hg;
    const float* W = (g == 0) ? Wr : (g == 1) ? Wz : Wg;
    int col   = nt * 16 + (lane & 15);
    int kbase = kt * 32 + (lane >> 4) * 8;
    half8 v;
#pragma unroll
    for (int i = 0; i < 8; ++i) {
        int k = kbase + i;
        float val = (k < 256) ? H[k * 256 + col] : W[(k - 256) * 256 + col];
        v[i] = (f16)val;
    }
    *(half8*)(B + (size_t)idx * 8) = v;
}

__global__ void __launch_bounds__(512, 1)
gru_scan(const float* __restrict__ x,
         const float* __restrict__ br, const float* __restrict__ bz,
         const float* __restrict__ bg,
         const f16* __restrict__ Bfrag,
         float* __restrict__ out) {
    __shared__ __align__(16) unsigned char sH[8192];
    __shared__ __align__(16) unsigned char sRH[8192];
    __shared__ __align__(16) unsigned char sX[2][2048];

    const int tid  = threadIdx.x;
    const int wave = tid >> 6;
    const int lane = tid & 63;
    const int cl   = lane & 15;
    const int rq   = lane >> 4;
    const int b0   = blockIdx.x * 16;
    const int nt0  = wave * 2, nt1 = wave * 2 + 1;
    const int col0 = nt0 * 16 + cl, col1 = nt1 * 16 + cl;

    const int abase = cl * 512;
    const int asw   = (cl & 7) << 4;

    const float bR0 = br[col0], bR1 = br[col1];
    const float bZ0 = bz[col0], bZ1 = bz[col1];
    const float bG0 = bg[col0], bG1 = bg[col1];

    const half8* Bb  = (const half8*)Bfrag;
    const half8* pR0 = Bb + (size_t)((0 * 16 + nt0) * 10) * 64 + lane;
    const half8* pR1 = Bb + (size_t)((0 * 16 + nt1) * 10) * 64 + lane;
    const half8* pZ0 = Bb + (size_t)((1 * 16 + nt0) * 10) * 64 + lane;
    const half8* pZ1 = Bb + (size_t)((1 * 16 + nt1) * 10) * 64 + lane;
    const half8* pG0 = Bb + (size_t)((2 * 16 + nt0) * 10) * 64 + lane;
    const half8* pG1 = Bb + (size_t)((2 * 16 + nt1) * 10) * 64 + lane;

    float h0_[4] = {0.f, 0.f, 0.f, 0.f};
    float h1_[4] = {0.f, 0.f, 0.f, 0.f};
    float zs0[4], zs1[4];

    { half8 zz = {}; *(half8*)(sH + tid * 16) = zz; }
    for (int i = tid; i < 16 * 256; i += 512) {
        int r = i >> 8, c = i & 255;
        out[((size_t)(b0 + r) * 512) * 256 + c] = 0.f;
    }
    {
        size_t xo = (size_t)(b0 + wave) * 32768 + lane;
        float a0 = x[xo], a1 = x[xo + (size_t)8 * 32768];
        *(f16*)(sX[0] + wave * 128       + ((lane * 2) ^ ((wave & 7) << 4))) = (f16)a0;
        *(f16*)(sX[0] + (wave + 8) * 128 + ((lane * 2) ^ ((wave & 7) << 4))) = (f16)a1;
    }
    __syncthreads();

    for (int t = 0; t < 511; ++t) {
        const int xb = t & 1;
        float xp0 = 0.f, xp1 = 0.f;
        if (t < 510) {
            size_t xo = (size_t)(b0 + wave) * 32768 + (size_t)(t + 1) * 64 + lane;
            xp0 = x[xo];
            xp1 = x[xo + (size_t)8 * 32768];
        }

        floatx4 aR0 = {0,0,0,0}, aR1 = {0,0,0,0}, aZ0 = {0,0,0,0}, aZ1 = {0,0,0,0};
        half8 xa0, xa1;
#pragma unroll
        for (int kt = 0; kt < 8; ++kt) {
            half8 av = *(const half8*)(sH + abase + ((kt * 64 + rq * 16) ^ asw));
            aR0 = MFMA16(av, pR0[kt * 64], aR0);
            aR1 = MFMA16(av, pR1[kt * 64], aR1);
            aZ0 = MFMA16(av, pZ0[kt * 64], aZ0);
            aZ1 = MFMA16(av, pZ1[kt * 64], aZ1);
        }
        xa0 = *(const half8*)(sX[xb] + cl * 128 + ((rq * 16) ^ asw));
        xa1 = *(const half8*)(sX[xb] + cl * 128 + ((64 + rq * 16) ^ asw));
        aR0 = MFMA16(xa0, pR0[8 * 64], aR0);  aR1 = MFMA16(xa0, pR1[8 * 64], aR1);
        aZ0 = MFMA16(xa0, pZ0[8 * 64], aZ0);  aZ1 = MFMA16(xa0, pZ1[8 * 64], aZ1);
        aR0 = MFMA16(xa1, pR0[9 * 64], aR0);  aR1 = MFMA16(xa1, pR1[9 * 64], aR1);
        aZ0 = MFMA16(xa1, pZ0[9 * 64], aZ0);  aZ1 = MFMA16(xa1, pZ1[9 * 64], aZ1);

        if (t < 510) {
            const int nb = xb ^ 1;
            *(f16*)(sX[nb] + wave * 128       + ((lane * 2) ^ ((wave & 7) << 4))) = (f16)xp0;
            *(f16*)(sX[nb] + (wave + 8) * 128 + ((lane * 2) ^ ((wave & 7) << 4))) = (f16)xp1;
        }

#pragma unroll
        for (int j = 0; j < 4; ++j) {
            const int row = rq * 4 + j;
            float r0 = 1.f / (1.f + __expf(-(aR0[j] + bR0)));
            float r1 = 1.f / (1.f + __expf(-(aR1[j] + bR1)));
            zs0[j]   = 1.f / (1.f + __expf(-(aZ0[j] + bZ0)));
            zs1[j]   = 1.f / (1.f + __expf(-(aZ1[j] + bZ1)));
            const int sw = (row & 7) << 4;
            *(f16*)(sRH + row * 512 + ((col0 * 2) ^ sw)) = (f16)(r0 * h0_[j]);
            *(f16*)(sRH + row * 512 + ((col1 * 2) ^ sw)) = (f16)(r1 * h1_[j]);
        }
        __syncthreads();

        floatx4 aG0 = {0,0,0,0}, aG1 = {0,0,0,0};
#pragma unroll
        for (int kt = 0; kt < 8; ++kt) {
            half8 av = *(const half8*)(sRH + abase + ((kt * 64 + rq * 16) ^ asw));
            aG0 = MFMA16(av, pG0[kt * 64], aG0);
            aG1 = MFMA16(av, pG1[kt * 64], aG1);
        }
        aG0 = MFMA16(xa0, pG0[8 * 64], aG0);  aG1 = MFMA16(xa0, pG1[8 * 64], aG1);
        aG0 = MFMA16(xa1, pG0[9 * 64], aG0);  aG1 = MFMA16(xa1, pG1[9 * 64], aG1);

#pragma unroll
        for (int j = 0; j < 4; ++j) {
            const int row = rq * 4 + j;
            float e0 = __expf(2.f * (aG0[j] + bG0));
            float g0 = 1.f - 2.f / (e0 + 1.f);
            float e1 = __expf(2.f * (aG1[j] + bG1));
            float g1 = 1.f - 2.f / (e1 + 1.f);
            float hn0 = h0_[j] + zs0[j] * (g0 - h0_[j]);
            float hn1 = h1_[j] + zs1[j] * (g1 - h1_[j]);
            h0_[j] = hn0;
            h1_[j] = hn1;
            const int sw = (row & 7) << 4;
            *(f16*)(sH + row * 512 + ((col0 * 2) ^ sw)) = (f16)hn0;
            *(f16*)(sH + row * 512 + ((col1 * 2) ^ sw)) = (f16)hn1;
            size_t ob = ((size_t)(b0 + row) * 512 + (t + 1)) * 256;
            out[ob + col0] = hn0;
            out[ob + col1] = hn1;
        }
        __syncthreads();
    }
}

extern "C" void kernel_launch(void* const* d_in, const int* in_sizes, int n_in,
                              void* d_out, int out_size, void* d_ws, size_t ws_size,
                              hipStream_t stream) {
    const float* x  = (const float*)d_in[0];
    const float* Wr = (const float*)d_in[1];
    const float* br = (const float*)d_in[2];
    const float* Wz = (const float*)d_in[3];
    const float* bz = (const float*)d_in[4];
    const float* Wg = (const float*)d_in[5];
    const float* bg = (const float*)d_in[6];
    const float* Hr = (const float*)d_in[7];
    const float* Hz = (const float*)d_in[8];
    const float* Hg = (const float*)d_in[9];
    float* out = (float*)d_out;

    if (ws_size >= WS_NEED) {
        f16* ws = (f16*)d_ws;
        gru_wprep<<<120, 256, 0, stream>>>(Wr, Wz, Wg, Hr, Hz, Hg, ws);
        gru_gates<<<511 * 16, 512, 0, stream>>>(x, br, bz, bg, ws);
        (void)hipFuncSetAttribute((const void*)gru_scan10,
                                  hipFuncAttributeMaxDynamicSharedMemorySize, 155648);
        gru_scan10<<<16, 512, 155648, stream>>>(ws, out);
    } else {
        f16* Bfrag = (f16*)d_ws;
        gru_prep<<<120, 256, 0, stream>>>(Wr, Wz, Wg, Hr, Hz, Hg, Bfrag);
        gru_scan<<<16, 512, 0, stream>>>(x, br, bz, bg, Bfrag, out);
    }
}